// Round 1
// baseline (1736.963 us; speedup 1.0000x reference)
//
#include <hip/hip_runtime.h>

// Synonym: top-5 cosine similarity over a 400000x300 fp32 embedding table,
// 512 queries. Pipeline:
//   P0 qprep : gather+normalize query rows -> qf (fp32) + qn (bf16, K-padded)
//   P1 score : fused (stream table once) bf16-MFMA scoring + row norms +
//              per-512-row-chunk top-8 candidates per query
//   P2 topk  : merge chunk candidates -> top-32, exact fp32 rescore, top-5 out
// Output buffer (all fp32): [512*5] top values, then [512*5] ids as floats.

#define VOCAB   400000
#define DIM     300
#define NQ      512
#define NKSTEP  10          // K padded to 320 = 10 steps of 32
#define QSTR    328         // bf16 query row stride (bank-conflict-friendly)
#define QFSTR   304         // fp32 query row stride
#define TOPK    5
#define BM      128         // queries per P1 block (4 query tiles)
#define CHUNK   512         // vocab rows per candidate chunk
#define NCH     782         // ceil(400000/512)
#define CK      8           // candidates kept per chunk per query
#define P1_BLOCKS 256

using f32x4 = __attribute__((ext_vector_type(4))) float;
using s16x8 = __attribute__((ext_vector_type(8))) short;

__device__ __forceinline__ unsigned short f2bf(float f) {
  unsigned int u = __builtin_bit_cast(unsigned int, f);
  u += 0x7fffu + ((u >> 16) & 1u);   // RNE to bf16
  return (unsigned short)(u >> 16);
}

// ---------------- Phase 0: query gather + normalize ----------------
__global__ __launch_bounds__(64)
void qprep_kernel(const float* __restrict__ emb, const int* __restrict__ wid,
                  float* __restrict__ qf, unsigned short* __restrict__ qn) {
  const int q = blockIdx.x;
  const int lane = threadIdx.x;           // one wave per query
  const long long w = (long long)wid[q];
  const float* row = emb + w * DIM;
  float x[5];
  double ss = 0.0;
#pragma unroll
  for (int j = 0; j < 5; ++j) {
    const int k = lane + 64 * j;
    x[j] = (k < DIM) ? row[k] : 0.0f;
    ss += (double)x[j] * (double)x[j];
  }
#pragma unroll
  for (int m = 1; m < 64; m <<= 1) ss += __shfl_xor(ss, m, 64);
  const double rinv = 1.0 / sqrt(ss);
#pragma unroll
  for (int j = 0; j < 5; ++j) {
    const int k = lane + 64 * j;
    if (k < DIM) {
      const float v = (float)((double)x[j] * rinv);
      qf[q * QFSTR + k] = v;
      qn[q * QSTR + k] = f2bf(v);
    }
  }
  if (lane < QSTR - DIM) qn[q * QSTR + DIM + lane] = 0;  // zero K-pad 300..327
}

// ---------------- Phase 1: fused bf16-MFMA scoring + chunk top-8 ----------------
// Grid: 256 blocks of 256 threads (4 waves). block = (mtile = bid&3, chunk set = bid>>2 + 64*t).
// Wave tile: 32 vocab rows (A operand, from global fp32 -> bf16) x 128 queries (B, from LDS).
__global__ __launch_bounds__(256, 1)
void score_kernel(const float* __restrict__ emb, const unsigned short* __restrict__ qn,
                  float* __restrict__ candV, int* __restrict__ candI) {
  __shared__ __align__(16) unsigned short qlds[BM * QSTR];  // 83968 B
  __shared__ float poolV[BM][33];                           // +1 pad vs bank conflicts
  __shared__ int   poolI[BM][33];

  const int tid  = threadIdx.x;
  const int wave = tid >> 6;
  const int lane = tid & 63;
  const int l15  = lane & 15;
  const int grp  = lane >> 4;
  const int mtile = blockIdx.x & 3;
  const int cb    = blockIdx.x >> 2;

  // stage this block's 128 normalized bf16 query rows into LDS
  {
    const uint4* src = (const uint4*)(qn + (size_t)mtile * BM * QSTR);
    uint4* dst = (uint4*)qlds;
    for (int i = tid; i < BM * QSTR * 2 / 16; i += 256) dst[i] = src[i];
  }
  __syncthreads();

  const f32x4 z4 = {0.f, 0.f, 0.f, 0.f};

  for (int c = cb; c < NCH; c += P1_BLOCKS / 4) {
    const int base = c * CHUNK;
    // per-lane running top-2 for each of this lane's 8 query columns
    float t0v[8], t1v[8]; int t0i[8], t1i[8];
#pragma unroll
    for (int qi = 0; qi < 8; ++qi) { t0v[qi] = -1e30f; t1v[qi] = -1e30f; t0i[qi] = 0; t1i[qi] = 0; }

    for (int s = 0; s < 4; ++s) {
      const int vbase = base + s * 128 + wave * 32;
      const int row0 = vbase + l15;
      const int row1 = row0 + 16;
      const bool ok0 = row0 < VOCAB;
      const bool ok1 = row1 < VOCAB;
      const float* p0 = emb + (size_t)(ok0 ? row0 : 0) * DIM;
      const float* p1 = emb + (size_t)(ok1 ? row1 : 0) * DIM;

      // hoist ALL K-loop global loads (40 dwordx4/wave in flight = deep prefetch)
      f32x4 ab[NKSTEP][4];
#pragma unroll
      for (int ks = 0; ks < NKSTEP; ++ks) {
        const int ko = ks * 32 + grp * 8;
        if (ks < NKSTEP - 1) {
          ab[ks][0] = ok0 ? *(const f32x4*)(p0 + ko)     : z4;
          ab[ks][1] = ok0 ? *(const f32x4*)(p0 + ko + 4) : z4;
          ab[ks][2] = ok1 ? *(const f32x4*)(p1 + ko)     : z4;
          ab[ks][3] = ok1 ? *(const f32x4*)(p1 + ko + 4) : z4;
        } else {  // K tail: elements 300..319 are zero
#pragma unroll
          for (int j = 0; j < 4; ++j) {
            const int ka = ko + j, kb = ko + 4 + j;
            ab[ks][0][j] = (ok0 && ka < DIM) ? p0[ka] : 0.f;
            ab[ks][1][j] = (ok0 && kb < DIM) ? p0[kb] : 0.f;
            ab[ks][2][j] = (ok1 && ka < DIM) ? p1[ka] : 0.f;
            ab[ks][3][j] = (ok1 && kb < DIM) ? p1[kb] : 0.f;
          }
        }
      }

      f32x4 acc[8][2];
#pragma unroll
      for (int qi = 0; qi < 8; ++qi) { acc[qi][0] = z4; acc[qi][1] = z4; }
      float ss0 = 0.f, ss1 = 0.f;  // sumsq of this lane's k-slice of its 2 rows

#pragma unroll
      for (int ks = 0; ks < NKSTEP; ++ks) {
        s16x8 a0, a1;
#pragma unroll
        for (int j = 0; j < 4; ++j) {
          ss0 += ab[ks][0][j] * ab[ks][0][j] + ab[ks][1][j] * ab[ks][1][j];
          ss1 += ab[ks][2][j] * ab[ks][2][j] + ab[ks][3][j] * ab[ks][3][j];
          a0[j]     = (short)f2bf(ab[ks][0][j]);
          a0[j + 4] = (short)f2bf(ab[ks][1][j]);
          a1[j]     = (short)f2bf(ab[ks][2][j]);
          a1[j + 4] = (short)f2bf(ab[ks][3][j]);
        }
        const char* bbase = (const char*)qlds + ks * 64 + grp * 16;
#pragma unroll
        for (int qi = 0; qi < 8; ++qi) {
          const s16x8 b = *(const s16x8*)(bbase + (qi * 16 + l15) * (QSTR * 2));
          acc[qi][0] = __builtin_amdgcn_mfma_f32_16x16x32_bf16(a0, b, acc[qi][0], 0, 0, 0);
          acc[qi][1] = __builtin_amdgcn_mfma_f32_16x16x32_bf16(a1, b, acc[qi][1], 0, 0, 0);
        }
      }

      // full row norms: combine k-slices across the 4 lane groups
      ss0 += __shfl_xor(ss0, 16, 64); ss0 += __shfl_xor(ss0, 32, 64);
      ss1 += __shfl_xor(ss1, 16, 64); ss1 += __shfl_xor(ss1, 32, 64);
      const float ri0 = (ok0 && ss0 > 0.f) ? rsqrtf(ss0) : 0.f;
      const float ri1 = (ok1 && ss1 > 0.f) ? rsqrtf(ss1) : 0.f;
      // redistribute: acc rows of this lane are vbase + vi*16 + grp*4 + r
      float nv0[4], nv1[4];
#pragma unroll
      for (int r = 0; r < 4; ++r) {
        nv0[r] = __shfl(ri0, grp * 4 + r, 64);
        nv1[r] = __shfl(ri1, grp * 4 + r, 64);
      }
      // scale + per-lane top-2 update (queries of this lane: qi*16 + l15)
#pragma unroll
      for (int qi = 0; qi < 8; ++qi) {
#pragma unroll
        for (int vi = 0; vi < 2; ++vi) {
#pragma unroll
          for (int r = 0; r < 4; ++r) {
            const int vg = vbase + vi * 16 + grp * 4 + r;
            float val = acc[qi][vi][r] * (vi ? nv1[r] : nv0[r]);
            if (vg >= VOCAB) val = -1e30f;
            if (val > t0v[qi]) {
              t1v[qi] = t0v[qi]; t1i[qi] = t0i[qi];
              t0v[qi] = val;     t0i[qi] = vg;
            } else if (val > t1v[qi]) {
              t1v[qi] = val; t1i[qi] = vg;
            }
          }
        }
      }
    } // s sub-tiles

    // dump per-lane top-2 -> pool[query][32]
#pragma unroll
    for (int qi = 0; qi < 8; ++qi) {
      const int qq = qi * 16 + l15;
      const int slot = wave * 8 + grp * 2;
      poolV[qq][slot] = t0v[qi];     poolI[qq][slot] = t0i[qi];
      poolV[qq][slot + 1] = t1v[qi]; poolI[qq][slot + 1] = t1i[qi];
    }
    __syncthreads();
    // merge 32 -> sorted top-8, write chunk candidates
    if (tid < BM) {
      float bv[CK]; int bi[CK];
#pragma unroll
      for (int j = 0; j < CK; ++j) { bv[j] = -1e30f; bi[j] = 0; }
      for (int i = 0; i < 32; ++i) {
        const float v = poolV[tid][i];
        if (v > bv[CK - 1]) {
          bv[CK - 1] = v; bi[CK - 1] = poolI[tid][i];
#pragma unroll
          for (int j = CK - 1; j > 0; --j) {
            if (bv[j] > bv[j - 1]) {
              const float tv = bv[j]; bv[j] = bv[j - 1]; bv[j - 1] = tv;
              const int ti = bi[j]; bi[j] = bi[j - 1]; bi[j - 1] = ti;
            }
          }
        }
      }
      const size_t off = ((size_t)c * NQ + (mtile * BM + tid)) * CK;
#pragma unroll
      for (int j = 0; j < CK; ++j) { candV[off + j] = bv[j]; candI[off + j] = bi[j]; }
    }
    __syncthreads();
  } // chunk loop
}

// ---------------- Phase 2: merge candidates, exact rescore, top-5 ----------------
__global__ __launch_bounds__(256)
void topk_kernel(const float* __restrict__ emb, const float* __restrict__ qf,
                 const float* __restrict__ candV, const int* __restrict__ candI,
                 float* __restrict__ out) {
  __shared__ float pV[256 * 6];
  __shared__ int   pI[256 * 6];
  __shared__ int   selI[32];
  __shared__ float resV[32];

  const int q = blockIdx.x;
  const int t = threadIdx.x;

  // per-thread top-6 over this query's 782*8 chunk candidates
  float bv[6]; int bi[6];
#pragma unroll
  for (int j = 0; j < 6; ++j) { bv[j] = -1e30f; bi[j] = -1; }
  for (int i = t; i < NCH * CK; i += 256) {
    const int c = i >> 3, j0 = i & 7;
    const size_t off = ((size_t)c * NQ + q) * CK + j0;
    const float v = candV[off];
    if (v > bv[5]) {
      bv[5] = v; bi[5] = candI[off];
#pragma unroll
      for (int j = 5; j > 0; --j) {
        if (bv[j] > bv[j - 1]) {
          const float tv = bv[j]; bv[j] = bv[j - 1]; bv[j - 1] = tv;
          const int ti = bi[j]; bi[j] = bi[j - 1]; bi[j - 1] = ti;
        }
      }
    }
  }
#pragma unroll
  for (int j = 0; j < 6; ++j) { pV[t * 6 + j] = bv[j]; pI[t * 6 + j] = bi[j]; }
  __syncthreads();

  // wave 0: extract global top-32 (approx values) from the 1536-entry pool
  if (t < 64) {
    for (int r = 0; r < 32; ++r) {
      float mv = -2e30f; int mp = 0;
      for (int i = t; i < 256 * 6; i += 64) {
        const float v = pV[i];
        if (v > mv) { mv = v; mp = i; }
      }
#pragma unroll
      for (int m = 1; m < 64; m <<= 1) {
        const float ov = __shfl_xor(mv, m, 64);
        const int   op = __shfl_xor(mp, m, 64);
        if (ov > mv) { mv = ov; mp = op; }
      }
      if (t == 0) { selI[r] = pI[mp]; pV[mp] = -2e30f; }
      __builtin_amdgcn_wave_barrier();
    }
  }
  __syncthreads();

  // exact fp32 rescore of 32 candidates: 8 threads per candidate
  {
    const int j = t >> 3, sub = t & 7;
    const int id = selI[j];
    float dot = 0.f, sq = 0.f;
    if (id >= 0) {
      const f32x4* e4 = (const f32x4*)(emb + (size_t)id * DIM);
      const f32x4* q4 = (const f32x4*)(qf + (size_t)q * QFSTR);
      for (int f = sub; f < DIM / 4; f += 8) {
        const f32x4 ev = e4[f], qv = q4[f];
        dot += ev[0]*qv[0] + ev[1]*qv[1] + ev[2]*qv[2] + ev[3]*qv[3];
        sq  += ev[0]*ev[0] + ev[1]*ev[1] + ev[2]*ev[2] + ev[3]*ev[3];
      }
    }
#pragma unroll
    for (int m = 1; m < 8; m <<= 1) {
      dot += __shfl_xor(dot, m, 64);
      sq  += __shfl_xor(sq, m, 64);
    }
    if (sub == 0)
      resV[j] = (id >= 0 && sq > 0.f) ? (float)((double)dot / sqrt((double)sq)) : -2e30f;
  }
  __syncthreads();

  // top-5 of 32, sorted descending; ids written AS FLOATS after the values block
  if (t == 0) {
#pragma unroll
    for (int r = 0; r < TOPK; ++r) {
      float mv = -3e30f; int mp = 0;
      for (int i = 0; i < 32; ++i) if (resV[i] > mv) { mv = resV[i]; mp = i; }
      out[q * TOPK + r] = mv;
      out[NQ * TOPK + q * TOPK + r] = (float)selI[mp];
      resV[mp] = -3e30f;
    }
  }
}

extern "C" void kernel_launch(void* const* d_in, const int* in_sizes, int n_in,
                              void* d_out, int out_size, void* d_ws, size_t ws_size,
                              hipStream_t stream) {
  (void)in_sizes; (void)n_in; (void)out_size; (void)ws_size;
  const float* emb = (const float*)d_in[0];
  const int* wid = (const int*)d_in[1];   // word_ids (int32); d_in[2] (k=5) hardcoded
  float* out = (float*)d_out;

  // workspace layout (26.6 MB total, 16B-aligned sections)
  char* ws = (char*)d_ws;
  unsigned short* qn = (unsigned short*)ws;                          // 512*328*2      = 335872
  float* qf    = (float*)(ws + 335872);                              // 512*304*4      = 622592
  float* candV = (float*)(ws + 335872 + 622592);                     // 782*512*8*4    = 12812288
  int*   candI = (int*)  (ws + 335872 + 622592 + 12812288);          // 782*512*8*4    = 12812288

  qprep_kernel<<<NQ, 64, 0, stream>>>(emb, wid, qf, qn);
  score_kernel<<<P1_BLOCKS, 256, 0, stream>>>(emb, qn, candV, candI);
  topk_kernel<<<NQ, 256, 0, stream>>>(emb, qf, candV, candI, out);
}

// Round 2
// 1090.551 us; speedup vs baseline: 1.5927x; 1.5927x over previous
//
#include <hip/hip_runtime.h>

// Synonym: top-5 cosine similarity, 512 queries x 400000x300 fp32 table.
// v2 pipeline:
//   P0a qprep  : gather+normalize query rows -> qf (fp32) + qn (bf16, K-pad 320)
//   P0b prenorm: table -> row-normalized bf16, swizzled in MFMA A-frag order
//                (244 MiB: fits Infinity Cache, so 4 query-tile passes are ~free)
//   P1  score  : lean MFMA scoring (64 rows x 64 q per wave), per-lane top-3
//                per ~390-row window -> global candidates (no LDS pool, no convert)
//   P2  topk   : scan 3072 cands/query -> top-32 -> exact fp32 rescore -> top-5
// Output (fp32): [512*5] values, then [512*5] ids written as floats.

#define VOCAB   400000
#define DIM     300
#define NQ      512
#define NT      25000      // 16-row tiles
#define TILE_U  5120       // u16 per swizzled tile (10 ksteps * 512)
#define QSTR    328        // bf16 query row stride
#define QFSTR   304        // fp32 query row stride
#define TOPK    5
#define NCAND   3072       // per-query cand slots: 64 blk * 4 rowgrp * 4 grp * 3

using f32x4 = __attribute__((ext_vector_type(4))) float;
using s16x8 = __attribute__((ext_vector_type(8))) short;

__device__ __forceinline__ unsigned short f2bf(float f) {
  unsigned int u = __builtin_bit_cast(unsigned int, f);
  u += 0x7fffu + ((u >> 16) & 1u);   // RNE to bf16
  return (unsigned short)(u >> 16);
}

__device__ __forceinline__ void ins3(float v, int id, float* tv, int* ti) {
  if (v > tv[2]) {
    if (v > tv[0]) {
      tv[2] = tv[1]; ti[2] = ti[1]; tv[1] = tv[0]; ti[1] = ti[0];
      tv[0] = v; ti[0] = id;
    } else if (v > tv[1]) {
      tv[2] = tv[1]; ti[2] = ti[1]; tv[1] = v; ti[1] = id;
    } else {
      tv[2] = v; ti[2] = id;
    }
  }
}

// ---------------- P0a: query gather + normalize ----------------
__global__ __launch_bounds__(64)
void qprep_kernel(const float* __restrict__ emb, const int* __restrict__ wid,
                  float* __restrict__ qf, unsigned short* __restrict__ qn) {
  const int q = blockIdx.x;
  const int lane = threadIdx.x;
  const long long w = (long long)wid[q];
  const float* row = emb + w * DIM;
  float x[5];
  double ss = 0.0;
#pragma unroll
  for (int j = 0; j < 5; ++j) {
    const int k = lane + 64 * j;
    x[j] = (k < DIM) ? row[k] : 0.0f;
    ss += (double)x[j] * (double)x[j];
  }
#pragma unroll
  for (int m = 1; m < 64; m <<= 1) ss += __shfl_xor(ss, m, 64);
  const double rinv = 1.0 / sqrt(ss);
#pragma unroll
  for (int j = 0; j < 5; ++j) {
    const int k = lane + 64 * j;
    if (k < DIM) {
      const float v = (float)((double)x[j] * rinv);
      qf[q * QFSTR + k] = v;
      qn[q * QSTR + k] = f2bf(v);
    }
  }
  if (lane < QSTR - DIM) qn[q * QSTR + DIM + lane] = 0;
}

// ---------------- P0b: table -> normalized bf16, A-frag swizzled ----------------
// Swizzle: tile t (16 rows), element (row=t*16+r, k=ks*32+grp*8+j) lives at
// u16 offset t*5120 + ks*512 + grp*128 + r*8 + j. A wave's A-frag load for
// (tile, ks) is then sw + t*5120 + ks*512 + lane*8 : one contiguous 1 KB read.
__global__ __launch_bounds__(256)
void prenorm_kernel(const float* __restrict__ emb, unsigned short* __restrict__ sw) {
  const int wave = threadIdx.x >> 6, lane = threadIdx.x & 63;
  const int t = blockIdx.x * 4 + wave;          // 6250 blocks * 4 = 25000 exact
  const int r = lane & 15, grp = lane >> 4;
  const float* row = emb + (size_t)(t * 16 + r) * DIM;

  float x[10][8];
  float ss = 0.f;
#pragma unroll
  for (int ks = 0; ks < 10; ++ks) {
    const int k0 = ks * 32 + grp * 8;
    if (k0 + 8 <= DIM) {
      const f32x4 u = *(const f32x4*)(row + k0);
      const f32x4 v = *(const f32x4*)(row + k0 + 4);
#pragma unroll
      for (int j = 0; j < 4; ++j) { x[ks][j] = u[j]; x[ks][j + 4] = v[j]; }
    } else {
#pragma unroll
      for (int j = 0; j < 8; ++j) {
        const int k = k0 + j;
        x[ks][j] = (k < DIM) ? row[k] : 0.0f;
      }
    }
#pragma unroll
    for (int j = 0; j < 8; ++j) ss += x[ks][j] * x[ks][j];
  }
  // row sumsq: partners are lanes r, r+16, r+32, r+48
  ss += __shfl_xor(ss, 16, 64);
  ss += __shfl_xor(ss, 32, 64);
  const float rinv = rsqrtf(ss);

  unsigned short* dst = sw + (size_t)t * TILE_U + lane * 8;
#pragma unroll
  for (int ks = 0; ks < 10; ++ks) {
    uint4 pk;
    unsigned int w0 = f2bf(x[ks][0] * rinv) | ((unsigned int)f2bf(x[ks][1] * rinv) << 16);
    unsigned int w1 = f2bf(x[ks][2] * rinv) | ((unsigned int)f2bf(x[ks][3] * rinv) << 16);
    unsigned int w2 = f2bf(x[ks][4] * rinv) | ((unsigned int)f2bf(x[ks][5] * rinv) << 16);
    unsigned int w3 = f2bf(x[ks][6] * rinv) | ((unsigned int)f2bf(x[ks][7] * rinv) << 16);
    pk.x = w0; pk.y = w1; pk.z = w2; pk.w = w3;
    *(uint4*)(dst + ks * 512) = pk;
  }
}

// ---------------- P1: MFMA score + per-window top-3 candidates ----------------
// Grid 256 blocks x 512 threads. block = (mtile = bid&3 [128-query tile],
// rb = bid>>2 [row stripe]). Wave = (rowgrp = w>>1) x (qhalf = w&1):
// 64 vocab rows x 64 queries, acc[qi 0..3][vi 0..3] of 16x16x32 bf16 MFMA.
// Per lane per qi: running top-3 over all 25 iters (~390-row window),
// written once to cand at kernel end.
__global__ __launch_bounds__(512, 2)
void score_kernel(const unsigned short* __restrict__ sw,
                  const unsigned short* __restrict__ qn,
                  float2* __restrict__ cand) {
  __shared__ __align__(16) unsigned short qlds[128 * QSTR];  // 83,968 B

  const int tid = threadIdx.x;
  const int wave = tid >> 6, lane = tid & 63;
  const int l15 = lane & 15, grp = lane >> 4;
  const int mtile = blockIdx.x & 3, rb = blockIdx.x >> 2;
  const int rowgrp = wave >> 1, qhalf = wave & 1;

  // stage 128 query rows (bf16) into LDS
  {
    const uint4* src = (const uint4*)(qn + (size_t)mtile * 128 * QSTR);
    uint4* dst = (uint4*)qlds;
    for (int i = tid; i < 128 * QSTR * 2 / 16; i += 512) dst[i] = src[i];
  }
  __syncthreads();

  float v3[4][3]; int i3[4][3];
#pragma unroll
  for (int qi = 0; qi < 4; ++qi)
#pragma unroll
    for (int j = 0; j < 3; ++j) { v3[qi][j] = -1e30f; i3[qi][j] = 0; }

  const s16x8 zz = {0, 0, 0, 0, 0, 0, 0, 0};
  const int qrow0 = qhalf * 64;

  for (int it = 0; it < 25; ++it) {
    const int tbase = it * 1024 + rb * 16 + rowgrp * 4;
    bool tv[4];
    const unsigned short* ap[4];
#pragma unroll
    for (int vi = 0; vi < 4; ++vi) {
      const int t = tbase + vi;
      tv[vi] = (t < NT);
      ap[vi] = sw + (size_t)(tv[vi] ? t : 0) * TILE_U + lane * 8;
    }

    f32x4 acc[4][4];
#pragma unroll
    for (int qi = 0; qi < 4; ++qi)
#pragma unroll
      for (int vi = 0; vi < 4; ++vi) acc[qi][vi] = {0.f, 0.f, 0.f, 0.f};

#pragma unroll
    for (int ks = 0; ks < 10; ++ks) {
      s16x8 a[4];
#pragma unroll
      for (int vi = 0; vi < 4; ++vi)
        a[vi] = tv[vi] ? *(const s16x8*)(ap[vi] + ks * 512) : zz;
      const unsigned short* bb = qlds + ks * 32 + grp * 8;
#pragma unroll
      for (int qi = 0; qi < 4; ++qi) {
        const s16x8 b = *(const s16x8*)(bb + (qrow0 + qi * 16 + l15) * QSTR);
#pragma unroll
        for (int vi = 0; vi < 4; ++vi)
          acc[qi][vi] = __builtin_amdgcn_mfma_f32_16x16x32_bf16(a[vi], b, acc[qi][vi], 0, 0, 0);
      }
    }

    // scan acc -> per-lane top-3 (C/D layout: row = tile*16 + grp*4 + r, col = query l15)
#pragma unroll
    for (int vi = 0; vi < 4; ++vi) {
      if (!tv[vi]) continue;
      const int rbase = (tbase + vi) * 16 + grp * 4;
#pragma unroll
      for (int qi = 0; qi < 4; ++qi) {
#pragma unroll
        for (int rr = 0; rr < 4; ++rr) {
          ins3(acc[qi][vi][rr], rbase + rr, &v3[qi][0], &i3[qi][0]);
        }
      }
    }
  }

  // write candidates: slot = rb*48 + rowgrp*12 + grp*3 + j
  const int slotbase = rb * 48 + rowgrp * 12 + grp * 3;
#pragma unroll
  for (int qi = 0; qi < 4; ++qi) {
    const int q = mtile * 128 + qhalf * 64 + qi * 16 + l15;
    float2* dst = cand + (size_t)q * NCAND + slotbase;
#pragma unroll
    for (int j = 0; j < 3; ++j) {
      float2 e; e.x = v3[qi][j]; e.y = __int_as_float(i3[qi][j]);
      dst[j] = e;
    }
  }
}

// ---------------- P2: merge candidates, exact rescore, top-5 ----------------
__global__ __launch_bounds__(256)
void topk_kernel(const float* __restrict__ emb, const float* __restrict__ qf,
                 const float2* __restrict__ cand, float* __restrict__ out) {
  __shared__ float pV[256 * 6];
  __shared__ int   pI[256 * 6];
  __shared__ int   selI[32];
  __shared__ float resV[32];

  const int q = blockIdx.x;
  const int t = threadIdx.x;
  const float2* cq = cand + (size_t)q * NCAND;

  // per-thread top-6 over 3072/256 = 12 entries
  float bv[6]; int bi[6];
#pragma unroll
  for (int j = 0; j < 6; ++j) { bv[j] = -1e30f; bi[j] = -1; }
  for (int i = t; i < NCAND; i += 256) {
    const float2 e = cq[i];
    const float v = e.x;
    if (v > bv[5]) {
      bv[5] = v; bi[5] = __float_as_int(e.y);
#pragma unroll
      for (int j = 5; j > 0; --j) {
        if (bv[j] > bv[j - 1]) {
          const float tv2 = bv[j]; bv[j] = bv[j - 1]; bv[j - 1] = tv2;
          const int ti2 = bi[j]; bi[j] = bi[j - 1]; bi[j - 1] = ti2;
        }
      }
    }
  }
#pragma unroll
  for (int j = 0; j < 6; ++j) { pV[t * 6 + j] = bv[j]; pI[t * 6 + j] = bi[j]; }
  __syncthreads();

  // wave 0: select top-32 (approx values) from the 1536-entry pool
  if (t < 64) {
    for (int r = 0; r < 32; ++r) {
      float mv = -2e30f; int mp = 0;
      for (int i = t; i < 256 * 6; i += 64) {
        const float v = pV[i];
        if (v > mv) { mv = v; mp = i; }
      }
#pragma unroll
      for (int m = 1; m < 64; m <<= 1) {
        const float ov = __shfl_xor(mv, m, 64);
        const int   op = __shfl_xor(mp, m, 64);
        if (ov > mv) { mv = ov; mp = op; }
      }
      if (t == 0) { selI[r] = pI[mp]; pV[mp] = -2e30f; }
      __builtin_amdgcn_wave_barrier();
    }
  }
  __syncthreads();

  // exact fp32 rescore of 32 candidates, 8 threads each
  {
    const int j = t >> 3, sub = t & 7;
    const int id = selI[j];
    float dot = 0.f, sq = 0.f;
    if (id >= 0) {
      const f32x4* e4 = (const f32x4*)(emb + (size_t)id * DIM);
      const f32x4* q4 = (const f32x4*)(qf + (size_t)q * QFSTR);
      for (int f = sub; f < DIM / 4; f += 8) {
        const f32x4 ev = e4[f], qv = q4[f];
        dot += ev[0]*qv[0] + ev[1]*qv[1] + ev[2]*qv[2] + ev[3]*qv[3];
        sq  += ev[0]*ev[0] + ev[1]*ev[1] + ev[2]*ev[2] + ev[3]*ev[3];
      }
    }
#pragma unroll
    for (int m = 1; m < 8; m <<= 1) {
      dot += __shfl_xor(dot, m, 64);
      sq  += __shfl_xor(sq, m, 64);
    }
    if (sub == 0)
      resV[j] = (id >= 0 && sq > 0.f) ? (float)((double)dot / sqrt((double)sq)) : -2e30f;
  }
  __syncthreads();

  if (t == 0) {
#pragma unroll
    for (int r = 0; r < TOPK; ++r) {
      float mv = -3e30f; int mp = 0;
      for (int i = 0; i < 32; ++i) if (resV[i] > mv) { mv = resV[i]; mp = i; }
      out[q * TOPK + r] = mv;
      out[NQ * TOPK + q * TOPK + r] = (float)selI[mp];
      resV[mp] = -3e30f;
    }
  }
}

extern "C" void kernel_launch(void* const* d_in, const int* in_sizes, int n_in,
                              void* d_out, int out_size, void* d_ws, size_t ws_size,
                              hipStream_t stream) {
  (void)in_sizes; (void)n_in; (void)out_size; (void)ws_size;
  const float* emb = (const float*)d_in[0];
  const int* wid = (const int*)d_in[1];   // word_ids; d_in[2] (k=5) hardcoded
  float* out = (float*)d_out;

  // workspace layout (total ~257 MiB):
  //   qn   @ 0         : 512*328*2   =    335,872
  //   qf   @ 335872    : 512*304*4   =    622,592
  //   cand @ 958464    : 512*3072*8  = 12,582,912
  //   sw   @ 13541376  : 25000*10240 = 256,000,000
  char* ws = (char*)d_ws;
  unsigned short* qn = (unsigned short*)ws;
  float*  qf   = (float*)(ws + 335872);
  float2* cand = (float2*)(ws + 958464);
  unsigned short* sw = (unsigned short*)(ws + 13541376);

  qprep_kernel<<<NQ, 64, 0, stream>>>(emb, wid, qf, qn);
  prenorm_kernel<<<NT / 4, 256, 0, stream>>>(emb, sw);
  score_kernel<<<256, 512, 0, stream>>>(sw, qn, cand);
  topk_kernel<<<NQ, 256, 0, stream>>>(emb, qf, cand, out);
}